// Round 1
// baseline (766.548 us; speedup 1.0000x reference)
//
#include <hip/hip_runtime.h>

#define NN 20000   // nodes per graph

// ---------------- CSR build ----------------

__global__ void k_count(const int* __restrict__ dst, long dst_bs,
                        int* __restrict__ counts, long cnt_bs, int E) {
    int b = blockIdx.z;
    const int* d = dst + (size_t)b * dst_bs;
    int* c = counts + (size_t)b * cnt_bs;
    for (int e = blockIdx.x * blockDim.x + threadIdx.x; e < E; e += gridDim.x * blockDim.x)
        atomicAdd(&c[d[e]], 1);
}

// one block (256 threads) per batch: exclusive scan of counts -> offs, cursor
// counts and cursor may alias (same buffer).
__global__ void k_scan(const int* __restrict__ counts, long cnt_bs,
                       int* __restrict__ offs, long off_bs,
                       int* __restrict__ cursor, long cur_bs, int n) {
    int b = blockIdx.z;
    const int* cnt = counts + (size_t)b * cnt_bs;
    int* off = offs + (size_t)b * off_bs;
    int* cur = cursor + (size_t)b * cur_bs;
    __shared__ int sums[256];
    int t = threadIdx.x;
    int chunk = (n + 255) / 256;
    int lo = t * chunk;
    int hi = min(lo + chunk, n);
    int s = 0;
    for (int i = lo; i < hi; i++) s += cnt[i];
    sums[t] = s;
    __syncthreads();
    for (int d2 = 1; d2 < 256; d2 <<= 1) {
        int x = (t >= d2) ? sums[t - d2] : 0;
        __syncthreads();
        sums[t] += x;
        __syncthreads();
    }
    if (t == 255) off[n] = sums[255];
    int run = sums[t] - s;  // exclusive prefix for this thread's chunk
    for (int i = lo; i < hi; i++) {
        int c = cnt[i];        // read before aliased write
        off[i] = run;
        cur[i] = run;
        run += c;
    }
}

__global__ void k_fill(const int* __restrict__ src, long src_bs,
                       const int* __restrict__ dst, long dst_bs,
                       int* __restrict__ cursor, long cur_bs,
                       int* __restrict__ elist, long el_bs, int E) {
    int b = blockIdx.z;
    const int* s = src + (size_t)b * src_bs;
    const int* d = dst + (size_t)b * dst_bs;
    int* cur = cursor + (size_t)b * cur_bs;
    int* el = elist + (size_t)b * el_bs;
    for (int e = blockIdx.x * blockDim.x + threadIdx.x; e < E; e += gridDim.x * blockDim.x) {
        int p = atomicAdd(&cur[d[e]], 1);
        el[p] = s[e];
    }
}

// ---------------- aggregation: one block per node, one thread per feature ----------------

__global__ void k_agg(const float* __restrict__ feat, long feat_bs,
                      const int* __restrict__ offs, long off_bs,
                      const int* __restrict__ elist, long el_bs,
                      float* __restrict__ outp, long out_bs, int F) {
    int b = blockIdx.z;
    int n = blockIdx.x;
    int t = threadIdx.x;  // 0..F-1
    const float* fp = feat + (size_t)b * feat_bs;
    const int* off = offs + (size_t)b * off_bs;
    const int* el = elist + (size_t)b * el_bs;
    int lo = off[n], hi = off[n + 1];
    float s = 0.f;
    for (int e = lo; e < hi; e++) {
        int sn = el[e];
        s += fp[(size_t)sn * F + t];
    }
    outp[(size_t)b * out_bs + (size_t)n * F + t] = s;
}

// ---------------- fp32 tiled GEMM: C[M,Ncols] = A[M,K] @ W[K,Ncols] + bias (opt relu) ----------------

template <bool RELU>
__global__ void k_gemm(const float* __restrict__ A, long A_bs,
                       const float* __restrict__ W,
                       const float* __restrict__ bias,
                       float* __restrict__ C, long C_bs,
                       int M, int K, int Ncols) {
    const int BM = 64, BN = 64, BK = 16;
    __shared__ float As[BK][BM + 1];
    __shared__ float Bs[BK][BN];
    int b = blockIdx.z;
    const float* Ab = A + (size_t)b * A_bs;
    float* Cb = C + (size_t)b * C_bs;
    int bm = blockIdx.x * BM;
    int bn = blockIdx.y * BN;
    int tid = threadIdx.x;
    int tx = tid % 16, ty = tid / 16;
    float acc[4][4] = {};
    for (int k0 = 0; k0 < K; k0 += BK) {
        // A tile: 64 rows x 16 cols (float4 per thread, transpose into LDS)
        {
            int r = tid / 4;
            int c4 = (tid % 4) * 4;
            int row = bm + r;
            float4 v = make_float4(0.f, 0.f, 0.f, 0.f);
            if (row < M) v = *(const float4*)&Ab[(size_t)row * K + k0 + c4];
            As[c4 + 0][r] = v.x;
            As[c4 + 1][r] = v.y;
            As[c4 + 2][r] = v.z;
            As[c4 + 3][r] = v.w;
        }
        // B tile: 16 rows x 64 cols
        {
            int r = tid / 16;
            int c4 = (tid % 16) * 4;
            float4 v = *(const float4*)&W[(size_t)(k0 + r) * Ncols + bn + c4];
            *(float4*)&Bs[r][c4] = v;
        }
        __syncthreads();
#pragma unroll
        for (int k = 0; k < BK; k++) {
            float a[4], bb[4];
#pragma unroll
            for (int i = 0; i < 4; i++) a[i] = As[k][ty + i * 16];
#pragma unroll
            for (int j = 0; j < 4; j++) bb[j] = Bs[k][tx + j * 16];
#pragma unroll
            for (int i = 0; i < 4; i++)
#pragma unroll
                for (int j = 0; j < 4; j++) acc[i][j] += a[i] * bb[j];
        }
        __syncthreads();
    }
#pragma unroll
    for (int i = 0; i < 4; i++) {
        int row = bm + ty + i * 16;
        if (row >= M) continue;
#pragma unroll
        for (int j = 0; j < 4; j++) {
            int col = bn + tx + j * 16;
            float v = acc[i][j] + bias[col];
            if (RELU) v = fmaxf(v, 0.f);
            Cb[(size_t)row * Ncols + col] = v;
        }
    }
}

// ---------------- host ----------------

extern "C" void kernel_launch(void* const* d_in, const int* in_sizes, int n_in,
                              void* d_out, int out_size, void* d_ws, size_t ws_size,
                              hipStream_t stream) {
    const float* features = (const float*)d_in[0];  // [B,N,128]
    const int* src = (const int*)d_in[1];           // [B,E]
    const int* dst = (const int*)d_in[2];           // [B,E]
    const float* W1 = (const float*)d_in[3];        // [128,256]
    const float* b1 = (const float*)d_in[4];        // [256]
    const float* W2 = (const float*)d_in[5];        // [256,128]
    const float* b2 = (const float*)d_in[6];        // [128]
    float* out = (float*)d_out;                     // [B,N,128]

    const int B = 4;
    const int N = NN;
    const int E = in_sizes[1] / B;

    auto need = [&](int nb) -> size_t {
        size_t f = (size_t)nb * N * (128 + 256 + 256) * sizeof(float);
        size_t i = (size_t)nb * ((size_t)(N + 1) + N + E) * sizeof(int);
        return f + i;
    };
    int nb = (ws_size >= need(4)) ? 4 : 1;
    int npass = B / nb;

    char* p = (char*)d_ws;
    float* A1 = (float*)p; p += (size_t)nb * N * 128 * sizeof(float);
    float* H  = (float*)p; p += (size_t)nb * N * 256 * sizeof(float);
    float* A2 = (float*)p; p += (size_t)nb * N * 256 * sizeof(float);
    int* offs = (int*)p;   p += (size_t)nb * (N + 1) * sizeof(int);
    int* curs = (int*)p;   p += (size_t)nb * N * sizeof(int);
    int* elist = (int*)p;

    for (int pass = 0; pass < npass; pass++) {
        int b0 = pass * nb;
        const float* feat_p = features + (size_t)b0 * N * 128;
        const int* src_p = src + (size_t)b0 * E;
        const int* dst_p = dst + (size_t)b0 * E;
        float* out_p = out + (size_t)b0 * N * 128;

        hipMemsetAsync(curs, 0, (size_t)nb * N * sizeof(int), stream);

        dim3 gE((E + 255) / 256, 1, nb);
        k_count<<<gE, 256, 0, stream>>>(dst_p, E, curs, N, E);
        k_scan<<<dim3(1, 1, nb), 256, 0, stream>>>(curs, N, offs, N + 1, curs, N, N);
        k_fill<<<gE, 256, 0, stream>>>(src_p, E, dst_p, E, curs, N, elist, E, E);

        // conv1 aggregation: A1 = segsum(feat[src] -> dst), F=128
        k_agg<<<dim3(N, 1, nb), 128, 0, stream>>>(feat_p, (long)N * 128, offs, N + 1,
                                                  elist, E, A1, (long)N * 128, 128);
        // conv1 linear + relu: H = relu(A1 @ W1 + b1)
        k_gemm<true><<<dim3((N + 63) / 64, 256 / 64, nb), 256, 0, stream>>>(
            A1, (long)N * 128, W1, b1, H, (long)N * 256, N, 128, 256);
        // conv2 aggregation: A2 = segsum(H[src] -> dst), F=256
        k_agg<<<dim3(N, 1, nb), 256, 0, stream>>>(H, (long)N * 256, offs, N + 1,
                                                  elist, E, A2, (long)N * 256, 256);
        // conv2 linear: out = A2 @ W2 + b2
        k_gemm<false><<<dim3((N + 63) / 64, 128 / 64, nb), 256, 0, stream>>>(
            A2, (long)N * 256, W2, b2, out_p, (long)N * 128, N, 256, 128);
    }
}

// Round 2
// 510.148 us; speedup vs baseline: 1.5026x; 1.5026x over previous
//
#include <hip/hip_runtime.h>

#define NN 20000   // nodes per graph

// ---------------- CSR build ----------------

__global__ void k_count(const int* __restrict__ dst, long dst_bs,
                        int* __restrict__ counts, long cnt_bs, int E) {
    int b = blockIdx.z;
    const int* d = dst + (size_t)b * dst_bs;
    int* c = counts + (size_t)b * cnt_bs;
    for (int e = blockIdx.x * blockDim.x + threadIdx.x; e < E; e += gridDim.x * blockDim.x)
        atomicAdd(&c[d[e]], 1);
}

// one block (256 threads) per batch: exclusive scan of counts -> offs, cursor
// counts and cursor may alias (same buffer).
__global__ void k_scan(const int* __restrict__ counts, long cnt_bs,
                       int* __restrict__ offs, long off_bs,
                       int* __restrict__ cursor, long cur_bs, int n) {
    int b = blockIdx.z;
    const int* cnt = counts + (size_t)b * cnt_bs;
    int* off = offs + (size_t)b * off_bs;
    int* cur = cursor + (size_t)b * cur_bs;
    __shared__ int sums[256];
    int t = threadIdx.x;
    int chunk = (n + 255) / 256;
    int lo = t * chunk;
    int hi = min(lo + chunk, n);
    int s = 0;
    for (int i = lo; i < hi; i++) s += cnt[i];
    sums[t] = s;
    __syncthreads();
    for (int d2 = 1; d2 < 256; d2 <<= 1) {
        int x = (t >= d2) ? sums[t - d2] : 0;
        __syncthreads();
        sums[t] += x;
        __syncthreads();
    }
    if (t == 255) off[n] = sums[255];
    int run = sums[t] - s;  // exclusive prefix for this thread's chunk
    for (int i = lo; i < hi; i++) {
        int c = cnt[i];        // read before aliased write
        off[i] = run;
        cur[i] = run;
        run += c;
    }
}

__global__ void k_fill(const int* __restrict__ src, long src_bs,
                       const int* __restrict__ dst, long dst_bs,
                       int* __restrict__ cursor, long cur_bs,
                       int* __restrict__ elist, long el_bs, int E) {
    int b = blockIdx.z;
    const int* s = src + (size_t)b * src_bs;
    const int* d = dst + (size_t)b * dst_bs;
    int* cur = cursor + (size_t)b * cur_bs;
    int* el = elist + (size_t)b * el_bs;
    for (int e = blockIdx.x * blockDim.x + threadIdx.x; e < E; e += gridDim.x * blockDim.x) {
        int p = atomicAdd(&cur[d[e]], 1);
        el[p] = s[e];
    }
}

// ---------------- aggregation, F=128: 32 lanes/node, float4, 2-edge unroll ----------------

__global__ void k_aggv(const float* __restrict__ feat, long feat_bs,
                       const int* __restrict__ offs, long off_bs,
                       const int* __restrict__ elist, long el_bs,
                       const float* __restrict__ bias,   // nullable
                       float* __restrict__ outp, long out_bs, int N) {
    int b = blockIdx.z;
    int g = threadIdx.x >> 5;        // node-group 0..7 within block
    int lane = threadIdx.x & 31;     // covers 4 floats each -> 128
    int n = blockIdx.x * 8 + g;
    if (n >= N) return;
    const float* fp = feat + (size_t)b * feat_bs;
    const int* off = offs + (size_t)b * off_bs;
    const int* el = elist + (size_t)b * el_bs;
    int lo = off[n], hi = off[n + 1];
    float4 a0 = make_float4(0.f, 0.f, 0.f, 0.f);
    float4 a1 = make_float4(0.f, 0.f, 0.f, 0.f);
    int e = lo;
    for (; e + 2 <= hi; e += 2) {
        int s0 = el[e], s1 = el[e + 1];
        float4 v0 = *(const float4*)&fp[(size_t)s0 * 128 + lane * 4];
        float4 v1 = *(const float4*)&fp[(size_t)s1 * 128 + lane * 4];
        a0.x += v0.x; a0.y += v0.y; a0.z += v0.z; a0.w += v0.w;
        a1.x += v1.x; a1.y += v1.y; a1.z += v1.z; a1.w += v1.w;
    }
    if (e < hi) {
        int s0 = el[e];
        float4 v0 = *(const float4*)&fp[(size_t)s0 * 128 + lane * 4];
        a0.x += v0.x; a0.y += v0.y; a0.z += v0.z; a0.w += v0.w;
    }
    float4 r;
    r.x = a0.x + a1.x; r.y = a0.y + a1.y; r.z = a0.z + a1.z; r.w = a0.w + a1.w;
    if (bias) {
        r.x += bias[lane * 4 + 0];
        r.y += bias[lane * 4 + 1];
        r.z += bias[lane * 4 + 2];
        r.w += bias[lane * 4 + 3];
    }
    *(float4*)&outp[(size_t)b * out_bs + (size_t)n * 128 + lane * 4] = r;
}

// ---------------- fp32 tiled GEMM: C[M,Ncols] = A[M,K] @ W[K,Ncols] + bias (opt relu) ----------------

template <bool RELU>
__global__ void k_gemm(const float* __restrict__ A, long A_bs,
                       const float* __restrict__ W,
                       const float* __restrict__ bias,   // nullable
                       float* __restrict__ C, long C_bs,
                       int M, int K, int Ncols) {
    const int BM = 64, BN = 64, BK = 16;
    __shared__ float As[BK][BM + 1];
    __shared__ float Bs[BK][BN];
    int b = blockIdx.z;
    const float* Ab = A + (size_t)b * A_bs;
    float* Cb = C + (size_t)b * C_bs;
    int bm = blockIdx.x * BM;
    int bn = blockIdx.y * BN;
    int tid = threadIdx.x;
    int tx = tid % 16, ty = tid / 16;
    float acc[4][4] = {};
    for (int k0 = 0; k0 < K; k0 += BK) {
        {
            int r = tid / 4;
            int c4 = (tid % 4) * 4;
            int row = bm + r;
            float4 v = make_float4(0.f, 0.f, 0.f, 0.f);
            if (row < M) v = *(const float4*)&Ab[(size_t)row * K + k0 + c4];
            As[c4 + 0][r] = v.x;
            As[c4 + 1][r] = v.y;
            As[c4 + 2][r] = v.z;
            As[c4 + 3][r] = v.w;
        }
        {
            int r = tid / 16;
            int c4 = (tid % 16) * 4;
            float4 v = *(const float4*)&W[(size_t)(k0 + r) * Ncols + bn + c4];
            *(float4*)&Bs[r][c4] = v;
        }
        __syncthreads();
#pragma unroll
        for (int k = 0; k < BK; k++) {
            float a[4], bb[4];
#pragma unroll
            for (int i = 0; i < 4; i++) a[i] = As[k][ty + i * 16];
#pragma unroll
            for (int j = 0; j < 4; j++) bb[j] = Bs[k][tx + j * 16];
#pragma unroll
            for (int i = 0; i < 4; i++)
#pragma unroll
                for (int j = 0; j < 4; j++) acc[i][j] += a[i] * bb[j];
        }
        __syncthreads();
    }
#pragma unroll
    for (int i = 0; i < 4; i++) {
        int row = bm + ty + i * 16;
        if (row >= M) continue;
#pragma unroll
        for (int j = 0; j < 4; j++) {
            int col = bn + tx + j * 16;
            float v = acc[i][j] + (bias ? bias[col] : 0.f);
            if (RELU) v = fmaxf(v, 0.f);
            Cb[(size_t)row * Ncols + col] = v;
        }
    }
}

// ---------------- host ----------------

extern "C" void kernel_launch(void* const* d_in, const int* in_sizes, int n_in,
                              void* d_out, int out_size, void* d_ws, size_t ws_size,
                              hipStream_t stream) {
    const float* features = (const float*)d_in[0];  // [B,N,128]
    const int* src = (const int*)d_in[1];           // [B,E]
    const int* dst = (const int*)d_in[2];           // [B,E]
    const float* W1 = (const float*)d_in[3];        // [128,256]
    const float* b1 = (const float*)d_in[4];        // [256]
    const float* W2 = (const float*)d_in[5];        // [256,128]
    const float* b2 = (const float*)d_in[6];        // [128]
    float* out = (float*)d_out;                     // [B,N,128]

    const int B = 4;
    const int N = NN;
    const int E = in_sizes[1] / B;

    auto need = [&](int nb) -> size_t {
        size_t f = (size_t)nb * N * (128 + 256 + 128) * sizeof(float);
        size_t i = (size_t)nb * ((size_t)(N + 1) + N + E) * sizeof(int);
        return f + i;
    };
    int nb = (ws_size >= need(4)) ? 4 : 1;
    int npass = B / nb;

    char* p = (char*)d_ws;
    float* A1 = (float*)p; p += (size_t)nb * N * 128 * sizeof(float);
    float* H  = (float*)p; p += (size_t)nb * N * 256 * sizeof(float);
    float* H2 = (float*)p; p += (size_t)nb * N * 128 * sizeof(float);
    int* offs = (int*)p;   p += (size_t)nb * (N + 1) * sizeof(int);
    int* curs = (int*)p;   p += (size_t)nb * N * sizeof(int);
    int* elist = (int*)p;

    for (int pass = 0; pass < npass; pass++) {
        int b0 = pass * nb;
        const float* feat_p = features + (size_t)b0 * N * 128;
        const int* src_p = src + (size_t)b0 * E;
        const int* dst_p = dst + (size_t)b0 * E;
        float* out_p = out + (size_t)b0 * N * 128;

        hipMemsetAsync(curs, 0, (size_t)nb * N * sizeof(int), stream);

        dim3 gE((E + 255) / 256, 1, nb);
        k_count<<<gE, 256, 0, stream>>>(dst_p, E, curs, N, E);
        k_scan<<<dim3(1, 1, nb), 256, 0, stream>>>(curs, N, offs, N + 1, curs, N, N);
        k_fill<<<gE, 256, 0, stream>>>(src_p, E, dst_p, E, curs, N, elist, E, E);

        dim3 gAgg((N + 7) / 8, 1, nb);
        // conv1 aggregation: A1 = segsum(feat[src] -> dst), F=128
        k_aggv<<<gAgg, 256, 0, stream>>>(feat_p, (long)N * 128, offs, N + 1,
                                         elist, E, nullptr, A1, (long)N * 128, N);
        // conv1 linear + relu: H = relu(A1 @ W1 + b1)
        k_gemm<true><<<dim3((N + 63) / 64, 256 / 64, nb), 256, 0, stream>>>(
            A1, (long)N * 128, W1, b1, H, (long)N * 256, N, 128, 256);
        // conv2 linear FIRST (agg is linear): H2 = H @ W2 (no bias)
        k_gemm<false><<<dim3((N + 63) / 64, 128 / 64, nb), 256, 0, stream>>>(
            H, (long)N * 256, W2, nullptr, H2, (long)N * 128, N, 256, 128);
        // conv2 aggregation + bias: out = segsum(H2[src] -> dst) + b2
        k_aggv<<<gAgg, 256, 0, stream>>>(H2, (long)N * 128, offs, N + 1,
                                         elist, E, b2, out_p, (long)N * 128, N);
    }
}

// Round 3
// 488.276 us; speedup vs baseline: 1.5699x; 1.0448x over previous
//
#include <hip/hip_runtime.h>

#define NN 20000   // nodes per graph

typedef __attribute__((ext_vector_type(8))) __bf16 bf16x8;
typedef __attribute__((ext_vector_type(4))) float f32x4;

__device__ __forceinline__ unsigned short f2bf(float f) {
    unsigned u = __builtin_bit_cast(unsigned, f);
    u += 0x7fff + ((u >> 16) & 1);   // round-to-nearest-even
    return (unsigned short)(u >> 16);
}
__device__ __forceinline__ float bf2f(unsigned short h) {
    unsigned u = ((unsigned)h) << 16;
    return __builtin_bit_cast(float, u);
}

// ---------------- CSR build ----------------

__global__ void k_count(const int* __restrict__ dst, long dst_bs,
                        int* __restrict__ counts, long cnt_bs, int E) {
    int b = blockIdx.z;
    const int* d = dst + (size_t)b * dst_bs;
    int* c = counts + (size_t)b * cnt_bs;
    for (int e = blockIdx.x * blockDim.x + threadIdx.x; e < E; e += gridDim.x * blockDim.x)
        atomicAdd(&c[d[e]], 1);
}

__global__ void k_scan(const int* __restrict__ counts, long cnt_bs,
                       int* __restrict__ offs, long off_bs,
                       int* __restrict__ cursor, long cur_bs, int n) {
    int b = blockIdx.z;
    const int* cnt = counts + (size_t)b * cnt_bs;
    int* off = offs + (size_t)b * off_bs;
    int* cur = cursor + (size_t)b * cur_bs;
    __shared__ int sums[256];
    int t = threadIdx.x;
    int chunk = (n + 255) / 256;
    int lo = t * chunk;
    int hi = min(lo + chunk, n);
    int s = 0;
    for (int i = lo; i < hi; i++) s += cnt[i];
    sums[t] = s;
    __syncthreads();
    for (int d2 = 1; d2 < 256; d2 <<= 1) {
        int x = (t >= d2) ? sums[t - d2] : 0;
        __syncthreads();
        sums[t] += x;
        __syncthreads();
    }
    if (t == 255) off[n] = sums[255];
    int run = sums[t] - s;
    for (int i = lo; i < hi; i++) {
        int c = cnt[i];
        off[i] = run;
        cur[i] = run;
        run += c;
    }
}

__global__ void k_fill(const int* __restrict__ src, long src_bs,
                       const int* __restrict__ dst, long dst_bs,
                       int* __restrict__ cursor, long cur_bs,
                       int* __restrict__ elist, long el_bs, int E) {
    int b = blockIdx.z;
    const int* s = src + (size_t)b * src_bs;
    const int* d = dst + (size_t)b * dst_bs;
    int* cur = cursor + (size_t)b * cur_bs;
    int* el = elist + (size_t)b * el_bs;
    for (int e = blockIdx.x * blockDim.x + threadIdx.x; e < E; e += gridDim.x * blockDim.x) {
        int p = atomicAdd(&cur[d[e]], 1);
        el[p] = s[e];
    }
}

// ---------------- aggregation, F=128: 32 lanes/node, float4, 2-edge unroll ----------------
// SPLIT: write hi/lo bf16 pair (o1=hi ushort, o2=lo ushort); else fp32 to o1.

template <bool SPLIT>
__global__ void k_aggv(const float* __restrict__ feat, long feat_bs,
                       const int* __restrict__ offs, long off_bs,
                       const int* __restrict__ elist, long el_bs,
                       const float* __restrict__ bias,   // nullable
                       void* __restrict__ o1, void* __restrict__ o2,
                       long out_bs, int N) {
    int b = blockIdx.z;
    int g = threadIdx.x >> 5;
    int lane = threadIdx.x & 31;
    int n = blockIdx.x * 8 + g;
    if (n >= N) return;
    const float* fp = feat + (size_t)b * feat_bs;
    const int* off = offs + (size_t)b * off_bs;
    const int* el = elist + (size_t)b * el_bs;
    int lo = off[n], hi = off[n + 1];
    float4 a0 = make_float4(0.f, 0.f, 0.f, 0.f);
    float4 a1 = make_float4(0.f, 0.f, 0.f, 0.f);
    int e = lo;
    for (; e + 2 <= hi; e += 2) {
        int s0 = el[e], s1 = el[e + 1];
        float4 v0 = *(const float4*)&fp[(size_t)s0 * 128 + lane * 4];
        float4 v1 = *(const float4*)&fp[(size_t)s1 * 128 + lane * 4];
        a0.x += v0.x; a0.y += v0.y; a0.z += v0.z; a0.w += v0.w;
        a1.x += v1.x; a1.y += v1.y; a1.z += v1.z; a1.w += v1.w;
    }
    if (e < hi) {
        int s0 = el[e];
        float4 v0 = *(const float4*)&fp[(size_t)s0 * 128 + lane * 4];
        a0.x += v0.x; a0.y += v0.y; a0.z += v0.z; a0.w += v0.w;
    }
    float4 r;
    r.x = a0.x + a1.x; r.y = a0.y + a1.y; r.z = a0.z + a1.z; r.w = a0.w + a1.w;
    if (bias) {
        r.x += bias[lane * 4 + 0];
        r.y += bias[lane * 4 + 1];
        r.z += bias[lane * 4 + 2];
        r.w += bias[lane * 4 + 3];
    }
    size_t oidx = (size_t)b * out_bs + (size_t)n * 128 + lane * 4;
    if (SPLIT) {
        union { unsigned short u[4]; uint2 v; } ph, pl;
        float f[4] = {r.x, r.y, r.z, r.w};
#pragma unroll
        for (int i = 0; i < 4; i++) {
            ph.u[i] = f2bf(f[i]);
            pl.u[i] = f2bf(f[i] - bf2f(ph.u[i]));
        }
        *(uint2*)((unsigned short*)o1 + oidx) = ph.v;
        *(uint2*)((unsigned short*)o2 + oidx) = pl.v;
    } else {
        *(float4*)((float*)o1 + oidx) = r;
    }
}

// ---------------- W prep: fp32 [K][N] -> transposed split bf16 [N][K] ----------------

__global__ void k_prep_w(const float* __restrict__ W1, const float* __restrict__ W2,
                         unsigned short* __restrict__ Wt1h, unsigned short* __restrict__ Wt1l,
                         unsigned short* __restrict__ Wt2h, unsigned short* __restrict__ Wt2l) {
    int i = blockIdx.x * 256 + threadIdx.x;
    if (i < 128 * 256) {
        {   // W1 [128][256] -> Wt1 [256][128]
            int k = i / 256, n = i % 256;
            float v = W1[i];
            unsigned short h = f2bf(v);
            Wt1h[n * 128 + k] = h;
            Wt1l[n * 128 + k] = f2bf(v - bf2f(h));
        }
        {   // W2 [256][128] -> Wt2 [128][256]
            int k = i / 128, n = i % 128;
            float v = W2[i];
            unsigned short h = f2bf(v);
            Wt2h[n * 256 + k] = h;
            Wt2l[n * 256 + k] = f2bf(v - bf2f(h));
        }
    }
}

// ---------------- split-bf16 MFMA GEMM (no LDS; W streamed from L2) ----------------
// C[M,NC] = (Ah+Al)[M,K] @ (Wh+Wl)[K,NC] (+bias, opt relu), dropping Al*Wl.
// A stored row-major bf16 hi/lo [M][K]; W stored TRANSPOSED [NC][K] bf16 hi/lo.
// Block: 256 thr = 4 waves, each wave owns MF*16 rows; BM = 64*MF.

template <int KSTEPS, int MF, int NFRAG, bool RELU, bool SPLIT_OUT>
__launch_bounds__(256)
__global__ void k_mfma(const unsigned short* __restrict__ Ah,
                       const unsigned short* __restrict__ Al, long A_bs,
                       const unsigned short* __restrict__ Wth,
                       const unsigned short* __restrict__ Wtl,
                       const float* __restrict__ bias,   // nullable
                       void* __restrict__ C1, void* __restrict__ C2, long C_bs, int M) {
    constexpr int K = KSTEPS * 32;
    constexpr int NC = NFRAG * 16;
    int b = blockIdx.z;
    int w = threadIdx.x >> 6, lane = threadIdx.x & 63;
    int colg = lane & 15, kg = lane >> 4;
    int r0 = blockIdx.x * (64 * MF) + w * (16 * MF);
    const unsigned short* Ahb = Ah + (size_t)b * A_bs;
    const unsigned short* Alb = Al + (size_t)b * A_bs;

    bf16x8 fah[MF][KSTEPS], fal[MF][KSTEPS];
#pragma unroll
    for (int mf = 0; mf < MF; mf++) {
        int row = r0 + mf * 16 + colg;
        if (row > M - 1) row = M - 1;           // clamp (stores are predicated)
        const unsigned short* ph = Ahb + (size_t)row * K + kg * 8;
        const unsigned short* pl = Alb + (size_t)row * K + kg * 8;
#pragma unroll
        for (int ks = 0; ks < KSTEPS; ks++) {
            fah[mf][ks] = *(const bf16x8*)(ph + ks * 32);
            fal[mf][ks] = *(const bf16x8*)(pl + ks * 32);
        }
    }

#pragma unroll 1
    for (int nf = 0; nf < NFRAG; nf++) {
        int c = nf * 16 + colg;
        const unsigned short* pwh = Wth + (size_t)c * K + kg * 8;
        const unsigned short* pwl = Wtl + (size_t)c * K + kg * 8;
        bf16x8 fwh[KSTEPS], fwl[KSTEPS];
#pragma unroll
        for (int ks = 0; ks < KSTEPS; ks++) {
            fwh[ks] = *(const bf16x8*)(pwh + ks * 32);
            fwl[ks] = *(const bf16x8*)(pwl + ks * 32);
        }
        f32x4 acc[MF];
#pragma unroll
        for (int mf = 0; mf < MF; mf++) acc[mf] = (f32x4){0.f, 0.f, 0.f, 0.f};
#pragma unroll
        for (int ks = 0; ks < KSTEPS; ks++)
#pragma unroll
            for (int mf = 0; mf < MF; mf++) {
                acc[mf] = __builtin_amdgcn_mfma_f32_16x16x32_bf16(fah[mf][ks], fwl[ks], acc[mf], 0, 0, 0);
                acc[mf] = __builtin_amdgcn_mfma_f32_16x16x32_bf16(fal[mf][ks], fwh[ks], acc[mf], 0, 0, 0);
                acc[mf] = __builtin_amdgcn_mfma_f32_16x16x32_bf16(fah[mf][ks], fwh[ks], acc[mf], 0, 0, 0);
            }
        float bv = bias ? bias[c] : 0.f;
#pragma unroll
        for (int mf = 0; mf < MF; mf++) {
            int rbase = r0 + mf * 16 + kg * 4;
#pragma unroll
            for (int j = 0; j < 4; j++) {
                int row = rbase + j;
                if (row < M) {
                    float v = acc[mf][j] + bv;
                    if (RELU) v = fmaxf(v, 0.f);
                    size_t ci = (size_t)b * C_bs + (size_t)row * NC + c;
                    if (SPLIT_OUT) {
                        unsigned short h = f2bf(v);
                        ((unsigned short*)C1)[ci] = h;
                        ((unsigned short*)C2)[ci] = f2bf(v - bf2f(h));
                    } else {
                        ((float*)C1)[ci] = v;
                    }
                }
            }
        }
    }
}

// ---------------- host ----------------

extern "C" void kernel_launch(void* const* d_in, const int* in_sizes, int n_in,
                              void* d_out, int out_size, void* d_ws, size_t ws_size,
                              hipStream_t stream) {
    const float* features = (const float*)d_in[0];  // [B,N,128]
    const int* src = (const int*)d_in[1];           // [B,E]
    const int* dst = (const int*)d_in[2];           // [B,E]
    const float* W1 = (const float*)d_in[3];        // [128,256]
    const float* b1 = (const float*)d_in[4];        // [256]
    const float* W2 = (const float*)d_in[5];        // [256,128]
    const float* b2 = (const float*)d_in[6];        // [128]
    float* out = (float*)d_out;                     // [B,N,128]

    const int B = 4;
    const int N = NN;
    const int E = in_sizes[1] / B;

    auto need = [&](int nb) -> size_t {
        size_t f32b = (size_t)nb * N * 128 * sizeof(float);                 // H2
        size_t bf = ((size_t)nb * N * 128 * 2 + (size_t)nb * N * 256 * 2)   // A1 + H hi/lo
                    * sizeof(unsigned short);
        size_t wt = 4 * 32768 * sizeof(unsigned short);
        size_t ints = (size_t)nb * ((size_t)(N + 1) + N + E) * sizeof(int);
        return f32b + bf + wt + ints;
    };
    int nb = (ws_size >= need(4)) ? 4 : 1;
    int npass = B / nb;

    char* p = (char*)d_ws;
    float* H2 = (float*)p;           p += (size_t)nb * N * 128 * sizeof(float);
    unsigned short* A1h = (unsigned short*)p; p += (size_t)nb * N * 128 * sizeof(unsigned short);
    unsigned short* A1l = (unsigned short*)p; p += (size_t)nb * N * 128 * sizeof(unsigned short);
    unsigned short* Hh  = (unsigned short*)p; p += (size_t)nb * N * 256 * sizeof(unsigned short);
    unsigned short* Hl  = (unsigned short*)p; p += (size_t)nb * N * 256 * sizeof(unsigned short);
    unsigned short* Wt1h = (unsigned short*)p; p += 32768 * sizeof(unsigned short);
    unsigned short* Wt1l = (unsigned short*)p; p += 32768 * sizeof(unsigned short);
    unsigned short* Wt2h = (unsigned short*)p; p += 32768 * sizeof(unsigned short);
    unsigned short* Wt2l = (unsigned short*)p; p += 32768 * sizeof(unsigned short);
    int* offs = (int*)p;  p += (size_t)nb * (N + 1) * sizeof(int);
    int* curs = (int*)p;  p += (size_t)nb * N * sizeof(int);
    int* elist = (int*)p;

    k_prep_w<<<128, 256, 0, stream>>>(W1, W2, Wt1h, Wt1l, Wt2h, Wt2l);

    for (int pass = 0; pass < npass; pass++) {
        int b0 = pass * nb;
        const float* feat_p = features + (size_t)b0 * N * 128;
        const int* src_p = src + (size_t)b0 * E;
        const int* dst_p = dst + (size_t)b0 * E;
        float* out_p = out + (size_t)b0 * N * 128;

        hipMemsetAsync(curs, 0, (size_t)nb * N * sizeof(int), stream);

        dim3 gE((E + 255) / 256, 1, nb);
        k_count<<<gE, 256, 0, stream>>>(dst_p, E, curs, N, E);
        k_scan<<<dim3(1, 1, nb), 256, 0, stream>>>(curs, N, offs, N + 1, curs, N, N);
        k_fill<<<gE, 256, 0, stream>>>(src_p, E, dst_p, E, curs, N, elist, E, E);

        dim3 gAgg((N + 7) / 8, 1, nb);
        // conv1 aggregation -> split bf16: (A1h, A1l) = segsum(feat[src] -> dst)
        k_aggv<true><<<gAgg, 256, 0, stream>>>(feat_p, (long)N * 128, offs, N + 1,
                                               elist, E, nullptr, A1h, A1l, (long)N * 128, N);
        // conv1 linear + bias + relu -> split bf16: (Hh, Hl)
        k_mfma<4, 2, 16, true, true><<<dim3((N + 127) / 128, 1, nb), 256, 0, stream>>>(
            A1h, A1l, (long)N * 128, Wt1h, Wt1l, b1, Hh, Hl, (long)N * 256, N);
        // conv2 linear (agg commutes): H2 = H @ W2, fp32
        k_mfma<8, 1, 8, false, false><<<dim3((N + 63) / 64, 1, nb), 256, 0, stream>>>(
            Hh, Hl, (long)N * 256, Wt2h, Wt2l, nullptr, H2, nullptr, (long)N * 128, N);
        // conv2 aggregation + bias: out = segsum(H2[src] -> dst) + b2
        k_aggv<false><<<gAgg, 256, 0, stream>>>(H2, (long)N * 128, offs, N + 1,
                                                elist, E, b2, out_p, nullptr, (long)N * 128, N);
    }
}